// Round 1
// baseline (102.866 us; speedup 1.0000x reference)
//
#include <hip/hip_runtime.h>
#include <math.h>

#define N    8192
#define DIM  64
#define KSEL 32

// ---------------------------------------------------------------------------
// Kernel A v3: v = tanh(3 * (emb[idx] @ W^T + b)) with ZERO LDS.
//   - lane l owns output dim l; W row l lives in 16 float4 VGPRs (loaded once
//     per wave from L2 -- W is shared by every block).
//   - embedding rows are wave-uniform -> readfirstlane-forced scalar pointer
//     -> s_load_dwordx4 on the constant-cache pipe; each v_fmac reads one
//     SGPR operand (legal: 1 scalar operand per VALU op).
//   - inner loop = pure 64-deep v_fmac chain (same FP order as prior kernel
//     -> bit-identical v1/v2).
// block = 256 (4 waves), each wave 8 rows -> 32 rows/block, grid = 2N/32 = 512.
// ---------------------------------------------------------------------------
__global__ __launch_bounds__(256) void embed_linear_tanh(
    const int*   __restrict__ idx,
    const float* __restrict__ emb1,
    const float* __restrict__ emb2,
    const float* __restrict__ W,     // [DIM][DIM], out[d] = dot(e, W[d,:]) + b[d]
    const float* __restrict__ b,
    float* __restrict__ v1,
    float* __restrict__ v2)
{
    const int t  = threadIdx.x;
    const int l  = t & 63;                                   // lane = output dim
    const int wv = __builtin_amdgcn_readfirstlane(t >> 6);   // wave 0..3
    const int m  = blockIdx.x & 1;                           // 0: emb1->v1, 1: emb2->v2
    const int rowbase = (int)(blockIdx.x >> 1) * 32;
    const float* __restrict__ emb  = m ? emb2 : emb1;
    float*       __restrict__ vout = m ? v2   : v1;

    // W row l -> 64 VGPRs (16 x dwordx4, L2-hit after first touch)
    float4 w[16];
    {
        const float4* Wr = (const float4*)(W + (size_t)l * DIM);
        #pragma unroll
        for (int q = 0; q < 16; ++q) w[q] = Wr[q];
    }
    const float bias = b[l];

    #pragma unroll
    for (int rr = 0; rr < 8; ++rr) {
        const int r = wv * 8 + rr;                           // wave-local row
        const int g = __builtin_amdgcn_readfirstlane(idx[rowbase + r]);
        const float* __restrict__ ep = emb + (size_t)g * DIM; // uniform -> s_load
        float acc = bias;
        #pragma unroll
        for (int q = 0; q < 16; ++q) {
            const float4 ev = ((const float4*)ep)[q];
            acc += ev.x * w[q].x;    // sequential fmac chain: identical FP
            acc += ev.y * w[q].y;    // order to the previous passing kernel
            acc += ev.z * w[q].z;
            acc += ev.w * w[q].w;
        }
        vout[(size_t)(rowbase + r) * DIM + l] = tanhf(3.0f * acc);
    }
}

// ---------------------------------------------------------------------------
// Kernel B v5: per-wave independent, zero barriers, zero staging.
//   - lane l pulls column (jbase+l) of v1/v2 straight from global into 128
//     VGPRs (L1/L2-resident: v1/v2 total 4 MB; first ~3 chunks shared by all
//     512 blocks). Replaces the LDS relay (2 syncthreads + 32 KB round trip
//     per chunk) of the prior version.
//   - each wave exits the chunk loop as soon as ITS 4 rows have 32 saturated
//     columns (~2.1 chunks expected) -- no coupling to sibling waves.
//   - colbuf is written and read by the same wave only -> no __syncthreads
//     anywhere.
// block = 256 (4 waves x 4 rows = 16 rows), grid = N/16 = 512 (2 blocks/CU).
// ---------------------------------------------------------------------------
__global__ __launch_bounds__(256, 2) void build_graph(
    const float* __restrict__ v1,
    const float* __restrict__ v2,
    float* __restrict__ out_rows,
    float* __restrict__ out_cols,
    float* __restrict__ out_data)
{
    __shared__ int colbuf[16][KSEL];     // row-private per wave; no cross-wave use

    const int t = threadIdx.x;
    const int l = t & 63;                // lane = column within chunk
    const int w = __builtin_amdgcn_readfirstlane(t >> 6);   // wave 0..3
    const int rowbase = (int)blockIdx.x * 16;

    int cnt[4] = {0, 0, 0, 0};           // per-row saturated count (wave-uniform)

    for (int cc = 0; cc < N / 64; ++cc) {
        const int jbase = cc * 64;

        // column (jbase+l) of v1,v2 -> registers (32 x dwordx4, L1/L2 hits)
        float4 c1r[16], c2r[16];
        {
            const float4* p1 = (const float4*)(v1 + (size_t)(jbase + l) * DIM);
            const float4* p2 = (const float4*)(v2 + (size_t)(jbase + l) * DIM);
            #pragma unroll
            for (int q = 0; q < 16; ++q) { c1r[q] = p1[q]; c2r[q] = p2[q]; }
        }

        bool all_done = true;
        #pragma unroll
        for (int rr = 0; rr < 4; ++rr) {
            if (cnt[rr] < KSEL) {                  // wave-uniform branch
                const int wrow = w * 4 + rr;
                const int i = rowbase + wrow;                          // uniform
                const float* __restrict__ r1 = v1 + (size_t)i * DIM;   // -> s_load
                const float* __restrict__ r2 = v2 + (size_t)i * DIM;
                float d1 = 0.f, d2 = 0.f;
                #pragma unroll
                for (int k4 = 0; k4 < 16; ++k4) {  // identical FP order to prior kernel
                    float4 b2 = c2r[k4];
                    d1 += r1[k4*4+0] * b2.x + r1[k4*4+1] * b2.y
                        + r1[k4*4+2] * b2.z + r1[k4*4+3] * b2.w;
                    float4 b1 = c1r[k4];
                    d2 += r2[k4*4+0] * b1.x + r2[k4*4+1] * b1.y
                        + r2[k4*4+2] * b1.z + r2[k4*4+3] * b1.w;
                }
                float a    = d1 - d2;
                float adjv = tanhf(3.0f * a);
                bool  sat  = (adjv == 1.0f);       // fp32 tanh saturation
                unsigned long long mask = __ballot(sat);
                int rank = (int)__popcll(mask & ((1ull << l) - 1ull));
                if (sat && (cnt[rr] + rank) < KSEL) colbuf[wrow][cnt[rr] + rank] = jbase + l;
                cnt[rr] += (int)__popcll(mask);
                if (cnt[rr] < KSEL) all_done = false;
            }
        }
        if (all_done) break;                       // wave-uniform exit
    }

    #pragma unroll
    for (int rr = 0; rr < 4; ++rr) {
        const int wrow = w * 4 + rr;
        const int i = rowbase + wrow;
        if (cnt[rr] >= KSEL) {
            if (l < KSEL) {
                int col = colbuf[wrow][l];         // ascending by construction
                size_t o = (size_t)i * KSEL + l;
                out_rows[o] = (float)i;
                out_cols[o] = (float)col;
                out_data[o] = 1.0f;                // saturated value, exact
            }
        } else if (l == 0) {
            // exact serial fallback: top-32 by (value desc, index asc), then col-sort.
            float bv[KSEL]; int bc[KSEL];
            #pragma unroll
            for (int k = 0; k < KSEL; ++k) { bv[k] = -1.0f; bc[k] = 0; }
            for (int j = 0; j < N; ++j) {
                float d1 = 0.f, d2 = 0.f;
                for (int k = 0; k < DIM; ++k) {
                    d1 += v1[(size_t)i * DIM + k] * v2[(size_t)j * DIM + k];
                    d2 += v2[(size_t)i * DIM + k] * v1[(size_t)j * DIM + k];
                }
                float adjv = fmaxf(tanhf(3.0f * (d1 - d2)), 0.0f);
                if (adjv > bv[KSEL - 1]) {         // strict: earlier equal index wins
                    int p = KSEL - 1;
                    while (p > 0 && bv[p - 1] < adjv) {
                        bv[p] = bv[p - 1]; bc[p] = bc[p - 1]; --p;
                    }
                    bv[p] = adjv; bc[p] = j;
                }
            }
            for (int x = 1; x < KSEL; ++x) {       // sort by column ascending
                float tv = bv[x]; int tc = bc[x]; int y = x - 1;
                while (y >= 0 && bc[y] > tc) { bv[y+1] = bv[y]; bc[y+1] = bc[y]; --y; }
                bv[y + 1] = tv; bc[y + 1] = tc;
            }
            for (int k = 0; k < KSEL; ++k) {
                size_t o = (size_t)i * KSEL + k;
                out_rows[o] = (float)i;
                out_cols[o] = (float)bc[k];
                out_data[o] = bv[k];
            }
        }
    }
}

// ---------------------------------------------------------------------------
extern "C" void kernel_launch(void* const* d_in, const int* in_sizes, int n_in,
                              void* d_out, int out_size, void* d_ws, size_t ws_size,
                              hipStream_t stream) {
    const int*   idx  = (const int*)  d_in[0];
    const float* emb1 = (const float*)d_in[1];
    const float* emb2 = (const float*)d_in[2];
    const float* w1   = (const float*)d_in[3];
    const float* b1   = (const float*)d_in[4];
    // d_in[5], d_in[6] = lin2_w / lin2_b -- unused by the reference (faithful).

    float* v1 = (float*)d_ws;                  // [N][DIM] fp32
    float* v2 = v1 + (size_t)N * DIM;          // [N][DIM] fp32  (4 MB total)

    float* out      = (float*)d_out;           // [2*N*K index | N*K data], all fp32
    float* out_rows = out;
    float* out_cols = out + (size_t)N * KSEL;
    float* out_data = out + (size_t)2 * N * KSEL;

    embed_linear_tanh<<<2 * N / 32, 256, 0, stream>>>(idx, emb1, emb2, w1, b1, v1, v2);
    build_graph<<<N / 16, 256, 0, stream>>>(v1, v2, out_rows, out_cols, out_data);
}

// Round 2
// 88.740 us; speedup vs baseline: 1.1592x; 1.1592x over previous
//
#include <hip/hip_runtime.h>
#include <math.h>

#define N    8192
#define DIM  64
#define KSEL 32

// ---------------------------------------------------------------------------
// Kernel A v4: v = tanh(3 * (emb[idx] @ W^T + b))
// Round-0 structure (coalesced staging, 16 rows/block, grid 1024) with the
// LDS read roles inverted -- this was round-0 A's dominant cost:
//   - W row l -> 16 float4 VGPRs, pulled ONCE per wave from a [64][68]-padded
//     LDS copy (16 ds_read_b128, 8-way conflict, one-time ~600 cy: irrelevant).
//   - e[r] read as ds_read_b128 BROADCASTS (wave-uniform address, conflict-
//     free) -- 16 LDS instrs/row instead of ~128 b32 reads.
// Inner loop: 64 v_fmac + 16 broadcast b128 per row -> VALU-issue-bound.
// FP accumulation order identical to the round-0 passing kernel
// (sequential k=0..63, then tanhf(3*acc)) -> v1/v2 bit-identical.
// ---------------------------------------------------------------------------
__global__ __launch_bounds__(256) void embed_linear_tanh(
    const int*   __restrict__ idx,
    const float* __restrict__ emb1,
    const float* __restrict__ emb2,
    const float* __restrict__ W,     // [DIM][DIM], out[d] = dot(e, W[d,:]) + b[d]
    const float* __restrict__ b,
    float* __restrict__ v1,
    float* __restrict__ v2)
{
    __shared__ float Wp[DIM][DIM + 4];   // +4 pad: rows stay 16B-aligned (272 B stride)
    __shared__ float e[16][DIM];         // broadcast reads (same addr per wave) -> no pad

    const int t = threadIdx.x;
    const int m = blockIdx.x & 1;                 // 0: emb1->v1, 1: emb2->v2
    const int rowbase = (int)(blockIdx.x >> 1) * 16;
    const float* __restrict__ emb  = m ? emb2 : emb1;
    float*       __restrict__ vout = m ? v2   : v1;

    // stage W (4096 floats) coalesced: 256 threads * 4 float4
    {
        const float4* W4 = (const float4*)W;
        #pragma unroll
        for (int s = 0; s < 4; ++s) {
            int e4 = t + s * 256;          // 0..1023
            float4 wvv = W4[e4];
            int d = e4 >> 4;
            int k = (e4 & 15) * 4;
            *(float4*)&Wp[d][k] = wvv;
        }
    }
    // stage 16 gathered emb rows (1024 floats): thread t -> row t>>4, float4 seg t&15
    {
        int r = t >> 4, seg = t & 15;
        int g = idx[rowbase + r];
        float4 x = ((const float4*)(emb + (size_t)g * DIM))[seg];
        *(float4*)&e[r][seg * 4] = x;
    }
    __syncthreads();

    const int l  = t & 63;   // lane = output dim
    const int wv = t >> 6;   // wave index

    // pull W row l into registers (one-time; 8-way LDS conflict acceptable)
    float4 w[16];
    #pragma unroll
    for (int q = 0; q < 16; ++q) w[q] = *(const float4*)&Wp[l][q * 4];
    const float bias = b[l];

    #pragma unroll
    for (int rr = 0; rr < 4; ++rr) {
        const int r = wv + rr * 4;         // same r across a wave -> e[] broadcast
        float acc = bias;
        #pragma unroll
        for (int q = 0; q < 16; ++q) {
            const float4 ev = *(const float4*)&e[r][q * 4];   // broadcast b128
            acc += ev.x * w[q].x;    // sequential fmac chain: identical FP
            acc += ev.y * w[q].y;    // order to the round-0 passing kernel
            acc += ev.z * w[q].z;
            acc += ev.w * w[q].w;
        }
        vout[(size_t)(rowbase + r) * DIM + l] = tanhf(3.0f * acc);
    }
}

// ---------------------------------------------------------------------------
// Kernel B v4 (round-0 proven version, byte-identical): R2 structure +
// scalar-path row vectors. LDS relay keeps global loads coalesced; per-wave
// column pull from LDS is conflict-free b128.
// ---------------------------------------------------------------------------
__global__ __launch_bounds__(256, 2) void build_graph(
    const float* __restrict__ v1,
    const float* __restrict__ v2,
    float* __restrict__ out_rows,
    float* __restrict__ out_cols,
    float* __restrict__ out_data)
{
    __shared__ float4 c1v[16][64];   // [k4][col] : lane l -> start bank 4l%32, conflict-free
    __shared__ float4 c2v[16][64];
    __shared__ int    colbuf[16][KSEL];
    __shared__ int    wdone[4];

    const int t = threadIdx.x;
    const int l = t & 63;            // lane
    const int w = __builtin_amdgcn_readfirstlane(t >> 6);   // wave 0..3, forced SGPR
    const int rowbase = (int)blockIdx.x * 16;

    if (l == 0) wdone[w] = 0;
    __syncthreads();

    int  cnt[4] = {0, 0, 0, 0};      // per-row saturated-count (wave-uniform)
    bool done = false;
    const int sr = t >> 2;           // staging: column row 0..63
    const int sq = t & 3;            // staging: 64B segment within row

    for (int cc = 0; cc < N / 64; ++cc) {
        const int jbase = cc * 64;
        // ---- cooperative staging: 64 column rows of v1,v2 -> LDS ----
        {
            const float4* p1 = (const float4*)(v1 + (size_t)(jbase + sr) * DIM) + sq * 4;
            const float4* p2 = (const float4*)(v2 + (size_t)(jbase + sr) * DIM) + sq * 4;
            #pragma unroll
            for (int s = 0; s < 4; ++s) {
                c1v[sq * 4 + s][sr] = p1[s];
                c2v[sq * 4 + s][sr] = p2[s];
            }
        }
        __syncthreads();

        if (!done) {
            // pull column (jbase+l) into registers: 32 conflict-free b128
            float4 c1r[16], c2r[16];
            #pragma unroll
            for (int k4 = 0; k4 < 16; ++k4) { c1r[k4] = c1v[k4][l]; c2r[k4] = c2v[k4][l]; }

            bool all_done = true;
            #pragma unroll
            for (int rr = 0; rr < 4; ++rr) {
                if (cnt[rr] < KSEL) {                 // wave-uniform branch
                    const int wrow = w * 4 + rr;
                    const int i = rowbase + wrow;                 // uniform
                    const float* __restrict__ r1 = v1 + (size_t)i * DIM;  // uniform -> s_load
                    const float* __restrict__ r2 = v2 + (size_t)i * DIM;
                    float d1 = 0.f, d2 = 0.f;
                    #pragma unroll
                    for (int k4 = 0; k4 < 16; ++k4) {
                        float4 b2 = c2r[k4];
                        d1 += r1[k4*4+0] * b2.x + r1[k4*4+1] * b2.y
                            + r1[k4*4+2] * b2.z + r1[k4*4+3] * b2.w;
                        float4 b1 = c1r[k4];
                        d2 += r2[k4*4+0] * b1.x + r2[k4*4+1] * b1.y
                            + r2[k4*4+2] * b1.z + r2[k4*4+3] * b1.w;
                    }
                    float a    = d1 - d2;
                    float adjv = tanhf(3.0f * a);
                    bool  sat  = (adjv == 1.0f);      // fp32 tanh saturation
                    unsigned long long mask = __ballot(sat);
                    int rank = (int)__popcll(mask & ((1ull << l) - 1ull));
                    if (sat && (cnt[rr] + rank) < KSEL) colbuf[wrow][cnt[rr] + rank] = jbase + l;
                    cnt[rr] += (int)__popcll(mask);
                    if (cnt[rr] < KSEL) all_done = false;
                }
            }
            if (all_done) { done = true; if (l == 0) wdone[w] = 1; }
        }
        __syncthreads();
        if (wdone[0] && wdone[1] && wdone[2] && wdone[3]) break;  // uniform
    }

    #pragma unroll
    for (int rr = 0; rr < 4; ++rr) {
        const int wrow = w * 4 + rr;
        const int i = rowbase + wrow;
        if (cnt[rr] >= KSEL) {
            if (l < KSEL) {
                int col = colbuf[wrow][l];       // ascending by construction
                size_t o = (size_t)i * KSEL + l;
                out_rows[o] = (float)i;
                out_cols[o] = (float)col;
                out_data[o] = 1.0f;              // saturated value, exact
            }
        } else if (l == 0) {
            // exact serial fallback: top-32 by (value desc, index asc), then col-sort.
            float bv[KSEL]; int bc[KSEL];
            #pragma unroll
            for (int k = 0; k < KSEL; ++k) { bv[k] = -1.0f; bc[k] = 0; }
            for (int j = 0; j < N; ++j) {
                float d1 = 0.f, d2 = 0.f;
                for (int k = 0; k < DIM; ++k) {
                    d1 += v1[(size_t)i * DIM + k] * v2[(size_t)j * DIM + k];
                    d2 += v2[(size_t)i * DIM + k] * v1[(size_t)j * DIM + k];
                }
                float adjv = fmaxf(tanhf(3.0f * (d1 - d2)), 0.0f);
                if (adjv > bv[KSEL - 1]) {       // strict: earlier equal index wins
                    int p = KSEL - 1;
                    while (p > 0 && bv[p - 1] < adjv) {
                        bv[p] = bv[p - 1]; bc[p] = bc[p - 1]; --p;
                    }
                    bv[p] = adjv; bc[p] = j;
                }
            }
            for (int x = 1; x < KSEL; ++x) {     // sort by column ascending
                float tv = bv[x]; int tc = bc[x]; int y = x - 1;
                while (y >= 0 && bc[y] > tc) { bv[y+1] = bv[y]; bc[y+1] = bc[y]; --y; }
                bv[y + 1] = tv; bc[y + 1] = tc;
            }
            for (int k = 0; k < KSEL; ++k) {
                size_t o = (size_t)i * KSEL + k;
                out_rows[o] = (float)i;
                out_cols[o] = (float)bc[k];
                out_data[o] = bv[k];
            }
        }
    }
}

// ---------------------------------------------------------------------------
extern "C" void kernel_launch(void* const* d_in, const int* in_sizes, int n_in,
                              void* d_out, int out_size, void* d_ws, size_t ws_size,
                              hipStream_t stream) {
    const int*   idx  = (const int*)  d_in[0];
    const float* emb1 = (const float*)d_in[1];
    const float* emb2 = (const float*)d_in[2];
    const float* w1   = (const float*)d_in[3];
    const float* b1   = (const float*)d_in[4];
    // d_in[5], d_in[6] = lin2_w / lin2_b -- unused by the reference (faithful).

    float* v1 = (float*)d_ws;                  // [N][DIM] fp32
    float* v2 = v1 + (size_t)N * DIM;          // [N][DIM] fp32  (4 MB total)

    float* out      = (float*)d_out;           // [2*N*K index | N*K data], all fp32
    float* out_rows = out;
    float* out_cols = out + (size_t)N * KSEL;
    float* out_data = out + (size_t)2 * N * KSEL;

    embed_linear_tanh<<<2 * N / 16, 256, 0, stream>>>(idx, emb1, emb2, w1, b1, v1, v2);
    build_graph<<<N / 16, 256, 0, stream>>>(v1, v2, out_rows, out_cols, out_data);
}